// Round 1
// baseline (276.209 us; speedup 1.0000x reference)
//
#include <hip/hip_runtime.h>
#include <hip/hip_bf16.h>

#define L 512
#define CS 256
#define CZ 128
#define LN_EPS 1e-5f

typedef __bf16 bf16_t;
typedef bf16_t bf16x8 __attribute__((ext_vector_type(8)));
typedef float f32x4 __attribute__((ext_vector_type(4)));
typedef unsigned short ushort_t;

__device__ inline float bf2f(ushort_t b) {
    unsigned int u = ((unsigned int)b) << 16;
    return __builtin_bit_cast(float, u);
}
__device__ inline ushort_t f2bf(float f) {
    unsigned int u = __builtin_bit_cast(unsigned int, f);
    u += 0x7fffu + ((u >> 16) & 1u);  // RNE
    return (ushort_t)(u >> 16);
}

// ---------------- Kernel A: s = gather-sum, LayerNorm -> u (bf16) ----------
__global__ __launch_bounds__(256) void k_embed_ln(
    const int* __restrict__ seq, const int* __restrict__ cid,
    const int* __restrict__ ridx,
    const float* __restrict__ Eaa, const float* __restrict__ Epos,
    const float* __restrict__ Ech, const float* __restrict__ lnw,
    const float* __restrict__ lnb,
    float* __restrict__ s_out, ushort_t* __restrict__ u_bf)
{
    int i = blockIdx.x;
    int c = threadIdx.x;
    int sq = seq[i], ri = ridx[i], ci = cid[i];
    float v = Eaa[sq * CS + c] + Epos[ri * CS + c] + Ech[ci * CS + c];
    s_out[i * CS + c] = v;

    float s1 = v, s2 = v * v;
    #pragma unroll
    for (int o = 32; o > 0; o >>= 1) {
        s1 += __shfl_down(s1, o, 64);
        s2 += __shfl_down(s2, o, 64);
    }
    __shared__ float red[8];
    int wave = c >> 6, lane = c & 63;
    if (lane == 0) { red[wave * 2] = s1; red[wave * 2 + 1] = s2; }
    __syncthreads();
    float S  = red[0] + red[2] + red[4] + red[6];
    float SS = red[1] + red[3] + red[5] + red[7];
    float mu  = S * (1.0f / CS);
    float var = SS * (1.0f / CS) - mu * mu;
    float rs  = rsqrtf(var + LN_EPS);
    float u   = (v - mu) * rs * lnw[c] + lnb[c];
    u_bf[i * CS + c] = f2bf(u);
}

// ---------------- Kernel C: W3^T (bf16) ------------------------------------
__global__ __launch_bounds__(256) void k_w3t(
    const float* __restrict__ Wp, ushort_t* __restrict__ w3t)
{
    int z = blockIdx.x;   // 0..127
    int c = threadIdx.x;  // 0..255
    w3t[z * CS + c] = f2bf(Wp[(2 * CS + c) * CZ + z]);
}

// ---------------- Kernel B: zrow = u@W1 + b, zcol = u@W2 -------------------
__global__ __launch_bounds__(256) void k_zrowcol(
    const ushort_t* __restrict__ u_bf, const float* __restrict__ Wp,
    const float* __restrict__ bp,
    float* __restrict__ zrow, float* __restrict__ zcol)
{
    __shared__ float su[8][CS];
    int i8 = blockIdx.x * 8;
    int t = threadIdx.x;
    #pragma unroll
    for (int ii = 0; ii < 8; ++ii) su[ii][t] = bf2f(u_bf[(i8 + ii) * CS + t]);
    __syncthreads();

    int z = t & 127;
    int half = t >> 7;  // 0 -> zrow(W1), 1 -> zcol(W2)
    const float* W = Wp + half * CS * CZ;
    float acc[8] = {0, 0, 0, 0, 0, 0, 0, 0};
    for (int c = 0; c < CS; ++c) {
        float w = W[c * CZ + z];
        #pragma unroll
        for (int ii = 0; ii < 8; ++ii) acc[ii] += su[ii][c] * w;
    }
    float* dst = half ? zcol : zrow;
    float bias = half ? 0.0f : bp[z];
    #pragma unroll
    for (int ii = 0; ii < 8; ++ii) dst[(i8 + ii) * CZ + z] = acc[ii] + bias;
}

// ---------------- Kernel D: pair tensor z ----------------------------------
// Grid (32,32): block = 16 i x 16 j x 128 z. 4 waves; wave owns z-half (4
// z-tiles, B-frags in 128 VGPRs) x 8 row-groups. Rowgroup = fixed i, m=lane&15
// indexes 16 j's. A-frag = u[i,c]*u[j0+m,c] built in fp32, packed to bf16.
__global__ __launch_bounds__(256, 2) void k_pair(
    const ushort_t* __restrict__ u_bf, const ushort_t* __restrict__ w3t,
    const float* __restrict__ zrow, const float* __restrict__ zcol,
    const float* __restrict__ Ecp, const float* __restrict__ Erp,
    const int* __restrict__ cid, const int* __restrict__ ridx,
    float* __restrict__ zout)
{
    const int tid = threadIdx.x;
    const int lane = tid & 63, wave = tid >> 6;
    const int m = lane & 15, q = lane >> 4;
    const int i0 = blockIdx.y * 16, j0 = blockIdx.x * 16;
    const int z0 = (wave & 1) * 64;        // z-half
    const int rbase = (wave >> 1) * 8;     // rowgroup range

    const bf16x8* pu = (const bf16x8*)u_bf;  // [512][32] frags
    const bf16x8* pw = (const bf16x8*)w3t;   // [128][32] frags

    // B fragments: W3T[z0+zt*16+m][kc*32 + q*8 .. +7]
    bf16x8 B[8][4];
    #pragma unroll
    for (int zt = 0; zt < 4; ++zt)
        #pragma unroll
        for (int kc = 0; kc < 8; ++kc)
            B[kc][zt] = pw[(z0 + zt * 16 + m) * 32 + kc * 4 + q];

    // u_j fragments (reused across all rowgroups)
    bf16x8 UJ[8];
    #pragma unroll
    for (int kc = 0; kc < 8; ++kc)
        UJ[kc] = pu[(j0 + m) * 32 + kc * 4 + q];

    // epilogue preloads: lane's j's are jb..jb+3 (C/D layout row = q*4+v)
    const int jb = j0 + q * 4;
    int CJ[4], RJ[4];
    float ZC[4][4];
    #pragma unroll
    for (int v = 0; v < 4; ++v) {
        CJ[v] = cid[jb + v];
        RJ[v] = ridx[jb + v];
        #pragma unroll
        for (int zt = 0; zt < 4; ++zt)
            ZC[v][zt] = zcol[(jb + v) * CZ + z0 + zt * 16 + m];
    }

    for (int rg = 0; rg < 8; ++rg) {
        const int i = i0 + rbase + rg;
        f32x4 acc[4] = {{0,0,0,0},{0,0,0,0},{0,0,0,0},{0,0,0,0}};

        bf16x8 uc = pu[i * 32 + q];  // rolling u_i prefetch
        #pragma unroll
        for (int kc = 0; kc < 8; ++kc) {
            bf16x8 un = uc;
            if (kc < 7) un = pu[i * 32 + (kc + 1) * 4 + q];
            bf16x8 a;
            #pragma unroll
            for (int e = 0; e < 8; ++e) {
                float p = (float)uc[e] * (float)UJ[kc][e];
                a[e] = (bf16_t)p;
            }
            acc[0] = __builtin_amdgcn_mfma_f32_16x16x32_bf16(a, B[kc][0], acc[0], 0, 0, 0);
            acc[1] = __builtin_amdgcn_mfma_f32_16x16x32_bf16(a, B[kc][1], acc[1], 0, 0, 0);
            acc[2] = __builtin_amdgcn_mfma_f32_16x16x32_bf16(a, B[kc][2], acc[2], 0, 0, 0);
            acc[3] = __builtin_amdgcn_mfma_f32_16x16x32_bf16(a, B[kc][3], acc[3], 0, 0, 0);
            uc = un;
        }

        // epilogue: z[i,j,z] = zx + zrow[i] + zcol[j] + Ecp[cp] + Erp[rp]
        const int ci = cid[i], ri = ridx[i];
        float zr[4];
        #pragma unroll
        for (int zt = 0; zt < 4; ++zt)
            zr[zt] = zrow[i * CZ + z0 + zt * 16 + m];
        float* obase = zout + ((size_t)i * L + jb) * CZ;
        #pragma unroll
        for (int v = 0; v < 4; ++v) {
            const int cp = ci * 2 + CJ[v];
            int d = ri - RJ[v];
            d = d < -32 ? -32 : (d > 32 ? 32 : d);
            const int rp = (ci == CJ[v]) ? (d + 32) : 65;
            const float* ecp = Ecp + cp * CZ;
            const float* erp = Erp + rp * CZ;
            float* orow = obase + (size_t)v * CZ;
            #pragma unroll
            for (int zt = 0; zt < 4; ++zt) {
                const int z = z0 + zt * 16 + m;
                orow[z] = acc[zt][v] + zr[zt] + ZC[v][zt] + ecp[z] + erp[z];
            }
        }
    }
}

extern "C" void kernel_launch(void* const* d_in, const int* in_sizes, int n_in,
                              void* d_out, int out_size, void* d_ws, size_t ws_size,
                              hipStream_t stream) {
    const int*   seq  = (const int*)d_in[0];
    const int*   cid  = (const int*)d_in[1];
    const int*   ridx = (const int*)d_in[2];
    const float* Eaa  = (const float*)d_in[3];
    const float* Epos = (const float*)d_in[4];
    const float* Ech  = (const float*)d_in[5];
    const float* Ecp  = (const float*)d_in[6];
    const float* Erp  = (const float*)d_in[7];
    const float* Wp   = (const float*)d_in[8];
    const float* bp   = (const float*)d_in[9];
    const float* lnw  = (const float*)d_in[10];
    const float* lnb  = (const float*)d_in[11];

    float* out   = (float*)d_out;
    float* s_out = out;
    float* zout  = out + L * CS;  // s is 512*256 floats, then z

    char* ws = (char*)d_ws;
    ushort_t* u_bf = (ushort_t*)ws;              // 256 KB
    ushort_t* w3t  = (ushort_t*)(ws + 262144);   // 64 KB
    float*    zrow = (float*)(ws + 327680);      // 256 KB
    float*    zcol = (float*)(ws + 589824);      // 256 KB

    hipLaunchKernelGGL(k_embed_ln, dim3(L), dim3(CS), 0, stream,
                       seq, cid, ridx, Eaa, Epos, Ech, lnw, lnb, s_out, u_bf);
    hipLaunchKernelGGL(k_w3t, dim3(CZ), dim3(CS), 0, stream, Wp, w3t);
    hipLaunchKernelGGL(k_zrowcol, dim3(L / 8), dim3(256), 0, stream,
                       u_bf, Wp, bp, zrow, zcol);
    hipLaunchKernelGGL(k_pair, dim3(32, 32), dim3(256), 0, stream,
                       u_bf, w3t, zrow, zcol, Ecp, Erp, cid, ridx, zout);
}

// Round 2
// 230.750 us; speedup vs baseline: 1.1970x; 1.1970x over previous
//
#include <hip/hip_runtime.h>
#include <hip/hip_bf16.h>

#define L 512
#define CS 256
#define CZ 128
#define LN_EPS 1e-5f

typedef __bf16 bf16_t;
typedef bf16_t bf16x8 __attribute__((ext_vector_type(8)));
typedef float f32x4 __attribute__((ext_vector_type(4)));
typedef unsigned short ushort_t;

__device__ inline ushort_t f2bf(float f) {
    unsigned int u = __builtin_bit_cast(unsigned int, f);
    u += 0x7fffu + ((u >> 16) & 1u);  // RNE
    return (ushort_t)(u >> 16);
}

// ---- Kernel S: embed + LN -> s, u_bf; zrow = u@W1 + b, zcol = u@W2 --------
// zi[i]/zj[i] depend only on u[i], so they fuse into the per-row block.
__global__ __launch_bounds__(256) void k_setup(
    const int* __restrict__ seq, const int* __restrict__ cid,
    const int* __restrict__ ridx,
    const float* __restrict__ Eaa, const float* __restrict__ Epos,
    const float* __restrict__ Ech, const float* __restrict__ lnw,
    const float* __restrict__ lnb, const float* __restrict__ Wp,
    const float* __restrict__ bp,
    float* __restrict__ s_out, ushort_t* __restrict__ u_bf,
    float* __restrict__ zrow, float* __restrict__ zcol)
{
    __shared__ float su[CS];
    __shared__ float red[8];
    const int i = blockIdx.x;
    const int c = threadIdx.x;
    const int sq = seq[i], ri = ridx[i], ci = cid[i];
    const float v = Eaa[sq * CS + c] + Epos[ri * CS + c] + Ech[ci * CS + c];
    s_out[i * CS + c] = v;

    float s1 = v, s2 = v * v;
    #pragma unroll
    for (int o = 32; o > 0; o >>= 1) {
        s1 += __shfl_down(s1, o, 64);
        s2 += __shfl_down(s2, o, 64);
    }
    const int wv = c >> 6, lane = c & 63;
    if (lane == 0) { red[wv * 2] = s1; red[wv * 2 + 1] = s2; }
    __syncthreads();
    const float S  = red[0] + red[2] + red[4] + red[6];
    const float SS = red[1] + red[3] + red[5] + red[7];
    const float mu  = S * (1.0f / CS);
    const float var = SS * (1.0f / CS) - mu * mu;
    const float rs  = rsqrtf(var + LN_EPS);
    const float u   = (v - mu) * rs * lnw[c] + lnb[c];
    u_bf[i * CS + c] = f2bf(u);
    su[c] = u;
    __syncthreads();

    const int z = c & 127;
    const int half = c >> 7;  // 0 -> zrow(W1), 1 -> zcol(W2)
    const float* W = Wp + half * CS * CZ;
    float acc = 0.0f;
    #pragma unroll 16
    for (int cc = 0; cc < CS; ++cc) acc += su[cc] * W[cc * CZ + z];
    if (half) zcol[i * CZ + z] = acc;
    else      zrow[i * CZ + z] = acc + bp[z];
}

// ---- Kernel T1: W3^T in bf16 (coalesced reads) ----------------------------
__global__ __launch_bounds__(128) void k_w3t(
    const float* __restrict__ Wp, ushort_t* __restrict__ w3t)
{
    const int c = blockIdx.x;   // 0..255
    const int z = threadIdx.x;  // 0..127
    w3t[z * CS + c] = f2bf(Wp[(2 * CS + c) * CZ + z]);
}

// ---- Kernel T2: tab[cp*66+rp] = Ecp[cp] + Erp[rp] -------------------------
__global__ __launch_bounds__(128) void k_tab(
    const float* __restrict__ Ecp, const float* __restrict__ Erp,
    float* __restrict__ tab)
{
    const int b = blockIdx.x;   // 0..263
    const int z = threadIdx.x;  // 0..127
    const int cp = b / 66, rp = b % 66;
    tab[b * CZ + z] = Ecp[cp * CZ + z] + Erp[rp * CZ + z];
}

// ---- Kernel P: pair tensor z ----------------------------------------------
// Grid (32,32): block = 16 i x 16 j x 128 z. 4 waves; wave owns z-half x
// 8 rowgroups. MFMA roles: A = W3T frags (M = z), B = u_i*u_j (N = j).
// C/D layout: col(lane&15) = j, row(q*4+v) = z -> 4 CONSECUTIVE z per lane,
// so epilogue loads/stores are all dwordx4. j fixed per lane -> zcol/cid/ridx
// hoisted out of the rg loop.
__global__ __launch_bounds__(256, 2) void k_pair(
    const ushort_t* __restrict__ u_bf, const ushort_t* __restrict__ w3t,
    const float* __restrict__ zrow, const float* __restrict__ zcol,
    const float* __restrict__ tab,
    const int* __restrict__ cid, const int* __restrict__ ridx,
    float* __restrict__ zout)
{
    const int tid = threadIdx.x;
    const int lane = tid & 63, wave = tid >> 6;
    const int m = lane & 15, q = lane >> 4;
    const int i0 = blockIdx.y * 16, j0 = blockIdx.x * 16;
    const int z0 = (wave & 1) * 64;        // z-half
    const int rbase = (wave >> 1) * 8;     // rowgroup range

    const bf16x8* pu = (const bf16x8*)u_bf;  // [512][32] k-frags
    const bf16x8* pw = (const bf16x8*)w3t;   // [128][32] k-frags

    // A fragments (W3T rows = z): A[kc][zt] = W3T[z0+zt*16+m][kc*32+q*8..+7]
    bf16x8 A[8][4];
    #pragma unroll
    for (int zt = 0; zt < 4; ++zt)
        #pragma unroll
        for (int kc = 0; kc < 8; ++kc)
            A[kc][zt] = pw[(z0 + zt * 16 + m) * 32 + kc * 4 + q];

    // u_j in fp32 (j = j0+m fixed per lane), reused by all rowgroups
    float UJf[8][8];
    #pragma unroll
    for (int kc = 0; kc < 8; ++kc) {
        bf16x8 uj = pu[(j0 + m) * 32 + kc * 4 + q];
        #pragma unroll
        for (int e = 0; e < 8; ++e) UJf[kc][e] = (float)uj[e];
    }

    const int j = j0 + m;
    const int cj = cid[j], rj = ridx[j];
    f32x4 ZC[4];
    #pragma unroll
    for (int zt = 0; zt < 4; ++zt)
        ZC[zt] = *(const f32x4*)&zcol[j * CZ + z0 + zt * 16 + q * 4];

    #pragma unroll 2
    for (int rg = 0; rg < 8; ++rg) {
        const int i = i0 + rbase + rg;
        const int ci = cid[i], ri = ridx[i];
        int d = ri - rj;
        d = d < -32 ? -32 : (d > 32 ? 32 : d);
        const int rp = (ci == cj) ? (d + 32) : 65;
        const int idx = (ci * 2 + cj) * 66 + rp;

        f32x4 acc[4] = {{0,0,0,0},{0,0,0,0},{0,0,0,0},{0,0,0,0}};
        #pragma unroll
        for (int kc = 0; kc < 8; ++kc) {
            bf16x8 ui = pu[i * 32 + kc * 4 + q];
            bf16x8 b;
            #pragma unroll
            for (int e = 0; e < 8; ++e)
                b[e] = (bf16_t)((float)ui[e] * UJf[kc][e]);
            acc[0] = __builtin_amdgcn_mfma_f32_16x16x32_bf16(A[kc][0], b, acc[0], 0, 0, 0);
            acc[1] = __builtin_amdgcn_mfma_f32_16x16x32_bf16(A[kc][1], b, acc[1], 0, 0, 0);
            acc[2] = __builtin_amdgcn_mfma_f32_16x16x32_bf16(A[kc][2], b, acc[2], 0, 0, 0);
            acc[3] = __builtin_amdgcn_mfma_f32_16x16x32_bf16(A[kc][3], b, acc[3], 0, 0, 0);
        }

        float* orow = zout + ((size_t)i * L + j) * CZ;
        #pragma unroll
        for (int zt = 0; zt < 4; ++zt) {
            const int zq = z0 + zt * 16 + q * 4;
            f32x4 zr = *(const f32x4*)&zrow[i * CZ + zq];
            f32x4 tb = *(const f32x4*)&tab[idx * CZ + zq];
            f32x4 o = acc[zt] + zr + ZC[zt] + tb;
            *(f32x4*)&orow[zq] = o;
        }
    }
}

extern "C" void kernel_launch(void* const* d_in, const int* in_sizes, int n_in,
                              void* d_out, int out_size, void* d_ws, size_t ws_size,
                              hipStream_t stream) {
    const int*   seq  = (const int*)d_in[0];
    const int*   cid  = (const int*)d_in[1];
    const int*   ridx = (const int*)d_in[2];
    const float* Eaa  = (const float*)d_in[3];
    const float* Epos = (const float*)d_in[4];
    const float* Ech  = (const float*)d_in[5];
    const float* Ecp  = (const float*)d_in[6];
    const float* Erp  = (const float*)d_in[7];
    const float* Wp   = (const float*)d_in[8];
    const float* bp   = (const float*)d_in[9];
    const float* lnw  = (const float*)d_in[10];
    const float* lnb  = (const float*)d_in[11];

    float* out   = (float*)d_out;
    float* s_out = out;
    float* zout  = out + L * CS;

    char* ws = (char*)d_ws;
    ushort_t* u_bf = (ushort_t*)ws;              // 256 KB
    ushort_t* w3t  = (ushort_t*)(ws + 262144);   // 64 KB
    float*    zrow = (float*)(ws + 327680);      // 256 KB
    float*    zcol = (float*)(ws + 589824);      // 256 KB
    float*    tab  = (float*)(ws + 851968);      // 132 KB

    hipLaunchKernelGGL(k_setup, dim3(L), dim3(256), 0, stream,
                       seq, cid, ridx, Eaa, Epos, Ech, lnw, lnb, Wp, bp,
                       s_out, u_bf, zrow, zcol);
    hipLaunchKernelGGL(k_w3t, dim3(CS), dim3(CZ), 0, stream, Wp, w3t);
    hipLaunchKernelGGL(k_tab, dim3(264), dim3(CZ), 0, stream, Ecp, Erp, tab);
    hipLaunchKernelGGL(k_pair, dim3(32, 32), dim3(256), 0, stream,
                       u_bf, w3t, zrow, zcol, tab, cid, ridx, zout);
}